// Round 1
// baseline (45.892 us; speedup 1.0000x reference)
//
#include <hip/hip_runtime.h>
#include <math.h>

#define NQ 4
#define DIN 256
#define DOUT 64
#define NLAYER 2
#define TPB 256

__device__ __forceinline__ float tanh_fast(float y) {
    // tanh(y) = 1 - 2/(exp(2y)+1); exact identity, ~1e-7 abs error in f32
    float e = __expf(2.0f * y);
    return 1.0f - 2.0f / (e + 1.0f);
}

__global__ __launch_bounds__(TPB) void qp_kernel(
    const float* __restrict__ x,  const float* __restrict__ W1,
    const float* __restrict__ b1, const float* __restrict__ wts,
    const float* __restrict__ W2, const float* __restrict__ b2,
    float* __restrict__ out)
{
    __shared__ __align__(16) float w1s[NQ][DIN];   // 4 KB
    __shared__ __align__(16) float fs[TPB][NQ];    // 4 KB
    __shared__ __align__(16) float qs[TPB][NQ];    // 4 KB
    __shared__ __align__(16) float w2s[DOUT][NQ];  // 1 KB
    __shared__ __align__(16) float us[8][8];       // Rot gates: (l*4+i) x {U00r,U00i,U01r,U01i,U10r,U10i,U11r,U11i}
    __shared__ float b2s[DOUT];
    __shared__ float b1s[NQ];

    const int t = threadIdx.x;
    const int brow = blockIdx.x * TPB;

    // ---- phase 0: stage weights, precompute Rot matrices (batch-independent)
    ((float4*)&w1s[0][0])[t] = ((const float4*)W1)[t];
    if (t < 64) {
        ((float4*)&w2s[0][0])[t] = ((const float4*)W2)[t];
        b2s[t] = b2[t];
    }
    if (t < NQ) b1s[t] = b1[t];
    if (t < 8) {
        // t = l*4 + i ; weights flat (L,4,3)
        const float phi = wts[t*3 + 0], th = wts[t*3 + 1], om = wts[t*3 + 2];
        float sth, cth; sincosf(0.5f*th, &sth, &cth);
        float sp, cp;   sincosf(0.5f*(phi+om), &sp, &cp);
        float sm, cm;   sincosf(0.5f*(phi-om), &sm, &cm);
        // U = RZ(om) RY(th) RZ(phi)
        us[t][0] =  cth*cp; us[t][1] = -cth*sp;   // U00 = c e^{-i(phi+om)/2}
        us[t][2] = -sth*cm; us[t][3] = -sth*sm;   // U01 = -s e^{+i(phi-om)/2}
        us[t][4] =  sth*cm; us[t][5] = -sth*sm;   // U10 =  s e^{-i(phi-om)/2}
        us[t][6] =  cth*cp; us[t][7] =  cth*sp;   // U11 = c e^{+i(phi+om)/2}
    }
    __syncthreads();

    // ---- phase 1: f = pi * tanh(x @ W1^T + b1) for this block's 256 rows
    {
        const int wave = t >> 6, lane = t & 63;
        const int rsub = lane >> 4;     // which of 4 rows this lane helps
        const int cc   = lane & 15;     // column chunk (float4 index within 64-col pass)
        #pragma unroll 2
        for (int it = 0; it < 16; ++it) {
            const int rloc = wave*64 + it*4 + rsub;
            const float4* xr = (const float4*)(x + (size_t)(brow + rloc) * DIN);
            float a0=0.f, a1=0.f, a2=0.f, a3=0.f;
            #pragma unroll
            for (int p = 0; p < 4; ++p) {
                const float4 xv  = xr[p*16 + cc];
                const float4 w0v = ((const float4*)&w1s[0][0])[p*16 + cc];
                const float4 w1v = ((const float4*)&w1s[1][0])[p*16 + cc];
                const float4 w2v = ((const float4*)&w1s[2][0])[p*16 + cc];
                const float4 w3v = ((const float4*)&w1s[3][0])[p*16 + cc];
                a0 = fmaf(xv.x,w0v.x, fmaf(xv.y,w0v.y, fmaf(xv.z,w0v.z, fmaf(xv.w,w0v.w, a0))));
                a1 = fmaf(xv.x,w1v.x, fmaf(xv.y,w1v.y, fmaf(xv.z,w1v.z, fmaf(xv.w,w1v.w, a1))));
                a2 = fmaf(xv.x,w2v.x, fmaf(xv.y,w2v.y, fmaf(xv.z,w2v.z, fmaf(xv.w,w2v.w, a2))));
                a3 = fmaf(xv.x,w3v.x, fmaf(xv.y,w3v.y, fmaf(xv.z,w3v.z, fmaf(xv.w,w3v.w, a3))));
            }
            #pragma unroll
            for (int d = 1; d < 16; d <<= 1) {
                a0 += __shfl_xor(a0, d, 64);
                a1 += __shfl_xor(a1, d, 64);
                a2 += __shfl_xor(a2, d, 64);
                a3 += __shfl_xor(a3, d, 64);
            }
            if (cc < NQ) {
                const float a = (cc == 0) ? a0 : (cc == 1) ? a1 : (cc == 2) ? a2 : a3;
                fs[rloc][cc] = 3.14159265358979f * tanh_fast(a + b1s[cc]);
            }
        }
    }
    __syncthreads();

    // ---- phase 2: 4-qubit statevector circuit, one thread per row
    {
        const float4 fv = ((const float4*)fs)[t];
        const float fq[4] = {fv.x, fv.y, fv.z, fv.w};
        const float IS2 = 0.70710678118654752f;
        float vr[4][2], vi[4][2];
        #pragma unroll
        for (int i = 0; i < 4; ++i) {
            // RZ(atan(f^2)) RY(atan(f)) H |0>, via cos(atan u)=rsqrt(1+u^2) + half-angle
            const float fi = fq[i];
            const float f2 = fi*fi;
            const float ca = rsqrtf(1.0f + f2);
            const float ch = sqrtf(0.5f*(1.0f + ca));
            const float sh = copysignf(sqrtf(fmaxf(0.5f*(1.0f - ca), 0.0f)), fi);
            const float cb = rsqrtf(1.0f + f2*f2);
            const float cbh = sqrtf(0.5f*(1.0f + cb));
            const float sbh = sqrtf(fmaxf(0.5f*(1.0f - cb), 0.0f)); // atan(f^2) >= 0
            const float u0 = (ch - sh) * IS2;
            const float u1 = (ch + sh) * IS2;
            vr[i][0] = u0 * cbh;  vi[i][0] = -u0 * sbh;
            vr[i][1] = u1 * cbh;  vi[i][1] =  u1 * sbh;
        }
        // tensor product -> 16 amplitudes; idx = i0*8 + i1*4 + i2*2 + i3
        float ar[16], ai[16];
        #pragma unroll
        for (int i0 = 0; i0 < 2; ++i0)
        #pragma unroll
        for (int i1 = 0; i1 < 2; ++i1) {
            const float pr  = vr[0][i0]*vr[1][i1] - vi[0][i0]*vi[1][i1];
            const float pim = vr[0][i0]*vi[1][i1] + vi[0][i0]*vr[1][i1];
            #pragma unroll
            for (int i2 = 0; i2 < 2; ++i2)
            #pragma unroll
            for (int i3 = 0; i3 < 2; ++i3) {
                const float qr  = vr[2][i2]*vr[3][i3] - vi[2][i2]*vi[3][i3];
                const float qim = vr[2][i2]*vi[3][i3] + vi[2][i2]*vr[3][i3];
                const int idx = i0*8 + i1*4 + i2*2 + i3;
                ar[idx] = pr*qr - pim*qim;
                ai[idx] = pr*qim + pim*qr;
            }
        }
        #pragma unroll
        for (int l = 0; l < NLAYER; ++l) {
            constexpr int cpairs[8][2] = {{0,1},{1,2},{2,3},{3,0},{0,2},{1,3},{2,0},{3,1}};
            #pragma unroll
            for (int g = 0; g < 8; ++g) {
                const int bc = 8 >> cpairs[g][0];
                const int bt = 8 >> cpairs[g][1];
                #pragma unroll
                for (int m = 0; m < 16; ++m) {
                    if ((m & bc) && !(m & bt)) {   // compile-time register swaps
                        const int m2 = m | bt;
                        float tr = ar[m]; ar[m] = ar[m2]; ar[m2] = tr;
                        float ti = ai[m]; ai[m] = ai[m2]; ai[m2] = ti;
                    }
                }
            }
            #pragma unroll
            for (int i = 0; i < 4; ++i) {
                const float* u = &us[l*4 + i][0];   // LDS broadcast (uniform address)
                const float u00r=u[0], u00i=u[1], u01r=u[2], u01i=u[3];
                const float u10r=u[4], u10i=u[5], u11r=u[6], u11i=u[7];
                const int bq = 8 >> i;
                #pragma unroll
                for (int m = 0; m < 16; ++m) {
                    if (!(m & bq)) {
                        const int m2 = m | bq;
                        const float a0r=ar[m], a0i=ai[m], a1r=ar[m2], a1i=ai[m2];
                        ar[m]  = u00r*a0r - u00i*a0i + u01r*a1r - u01i*a1i;
                        ai[m]  = u00r*a0i + u00i*a0r + u01r*a1i + u01i*a1r;
                        ar[m2] = u10r*a0r - u10i*a0i + u11r*a1r - u11i*a1i;
                        ai[m2] = u10r*a0i + u10i*a0r + u11r*a1i + u11i*a1r;
                    }
                }
            }
        }
        float z0=0.f, z1=0.f, z2=0.f, z3=0.f;
        #pragma unroll
        for (int m = 0; m < 16; ++m) {
            const float p = ar[m]*ar[m] + ai[m]*ai[m];
            z0 += (m & 8) ? -p : p;
            z1 += (m & 4) ? -p : p;
            z2 += (m & 2) ? -p : p;
            z3 += (m & 1) ? -p : p;
        }
        float4 qv; qv.x=z0; qv.y=z1; qv.z=z2; qv.w=z3;
        ((float4*)qs)[t] = qv;
    }

    // ---- phase 3: out = q @ W2^T + b2, coalesced float4 stores
    const int j4 = t & 15;             // fixed column group per thread
    float w2r[4][4], b2r[4];
    #pragma unroll
    for (int jj = 0; jj < 4; ++jj) {
        const int j = j4*4 + jj;
        #pragma unroll
        for (int i = 0; i < 4; ++i) w2r[jj][i] = w2s[j][i];
        b2r[jj] = b2s[j];
    }
    __syncthreads();
    const int rb = t >> 4;
    #pragma unroll 4
    for (int e = 0; e < 16; ++e) {
        const int r = e*16 + rb;
        const float4 q = ((const float4*)qs)[r];
        float4 o;
        o.x = fmaf(q.x,w2r[0][0], fmaf(q.y,w2r[0][1], fmaf(q.z,w2r[0][2], fmaf(q.w,w2r[0][3], b2r[0]))));
        o.y = fmaf(q.x,w2r[1][0], fmaf(q.y,w2r[1][1], fmaf(q.z,w2r[1][2], fmaf(q.w,w2r[1][3], b2r[1]))));
        o.z = fmaf(q.x,w2r[2][0], fmaf(q.y,w2r[2][1], fmaf(q.z,w2r[2][2], fmaf(q.w,w2r[2][3], b2r[2]))));
        o.w = fmaf(q.x,w2r[3][0], fmaf(q.y,w2r[3][1], fmaf(q.z,w2r[3][2], fmaf(q.w,w2r[3][3], b2r[3]))));
        ((float4*)(out + (size_t)(brow + r) * DOUT))[j4] = o;
    }
}

extern "C" void kernel_launch(void* const* d_in, const int* in_sizes, int n_in,
                              void* d_out, int out_size, void* d_ws, size_t ws_size,
                              hipStream_t stream) {
    const float* x  = (const float*)d_in[0];
    const float* W1 = (const float*)d_in[1];
    const float* b1 = (const float*)d_in[2];
    const float* wt = (const float*)d_in[3];
    const float* W2 = (const float*)d_in[4];
    const float* b2 = (const float*)d_in[5];
    float* out = (float*)d_out;
    const int B = in_sizes[0] / DIN;        // 131072
    qp_kernel<<<B / TPB, TPB, 0, stream>>>(x, W1, b1, wt, W2, b2, out);
}